// Round 17
// baseline (333.374 us; speedup 1.0000x reference)
//
#include <hip/hip_runtime.h>
#include <hip/hip_bf16.h>
#include <stdint.h>

// B=4, S=8192, E=1024, heads=16 -> math collapses to:
//   Q = x @ W1[0:1024].T ; A = per-64-col-block softmax(Q/4) ; out = A @ W2.T
static constexpr int MTOT = 32768;
static constexpr int KD   = 1024;
static constexpr int ND   = 1024;

static constexpr int BM = 256, BN = 256, BK = 64;
static constexpr int NT = KD / BK;              // 16 K-tiles (even)
static constexpr int ABUF = 32768;              // one A buffer (256x64 bf16)
static constexpr int HALF = 16384;              // one A unit (128 rows x 64 cols)

typedef __bf16 bf16x8 __attribute__((ext_vector_type(8)));
typedef float  f32x4  __attribute__((ext_vector_type(4)));

__device__ __forceinline__ unsigned short f2bf_rne(float f) {
  union { float f; uint32_t u; } c; c.f = f;
  uint32_t u = c.u;
  return (unsigned short)((u + 0x7fffu + ((u >> 16) & 1u)) >> 16);
}

// Cast x -> bf16 row-major; pack W1q/W2 -> frag-major bf16:
//   chunk c = ((n16*16 + kt)*2 + ks)*64 + lane  holds
//   W[n16*16 + (lane&15)][kt*64 + ks*32 + (lane>>4)*8 .. +8]
// so a wave's MFMA B-frag load is 64 consecutive 16B = 1KB contiguous.
__global__ void prep(const float* __restrict__ x,
                     const float* __restrict__ W1,
                     const float* __restrict__ W2,
                     unsigned short* __restrict__ xb,
                     unsigned short* __restrict__ w1p,
                     unsigned short* __restrict__ w2p) {
  constexpr int n4x = MTOT * KD / 4;
  constexpr int nChunk = (KD >> 4) * NT * 2 * 64;   // 131072 per matrix
  const int idx = blockIdx.x * blockDim.x + threadIdx.x;
  const int stride = gridDim.x * blockDim.x;
  for (int i = idx; i < n4x; i += stride) {
    float4 v = reinterpret_cast<const float4*>(x)[i];
    ushort4 o;
    o.x = f2bf_rne(v.x); o.y = f2bf_rne(v.y);
    o.z = f2bf_rne(v.z); o.w = f2bf_rne(v.w);
    reinterpret_cast<ushort4*>(xb)[i] = o;
  }
  for (int i = idx; i < 2 * nChunk; i += stride) {
    const int m = (i >= nChunk) ? 1 : 0;
    const int c = i - m * nChunk;
    const float* W = m ? W2 : W1;            // W1 rows 0..1023 = Wq
    unsigned short* P = m ? w2p : w1p;
    const int lane = c & 63;
    const int ks   = (c >> 6) & 1;
    const int kt   = (c >> 7) & 15;
    const int n16  = c >> 11;
    const int row  = n16 * 16 + (lane & 15);
    const int k    = kt * 64 + ks * 32 + (lane >> 4) * 8;
    const float* s = W + (size_t)row * KD + k;
    float4 v0 = reinterpret_cast<const float4*>(s)[0];
    float4 v1 = reinterpret_cast<const float4*>(s)[1];
    ushort4 o0, o1;
    o0.x = f2bf_rne(v0.x); o0.y = f2bf_rne(v0.y);
    o0.z = f2bf_rne(v0.z); o0.w = f2bf_rne(v0.w);
    o1.x = f2bf_rne(v1.x); o1.y = f2bf_rne(v1.y);
    o1.z = f2bf_rne(v1.z); o1.w = f2bf_rne(v1.w);
    reinterpret_cast<ushort4*>(P + (size_t)c * 8)[0] = o0;
    reinterpret_cast<ushort4*>(P + (size_t)c * 8)[1] = o1;
  }
}

__device__ __forceinline__ void gload_lds16(const void* g, void* lds) {
  __builtin_amdgcn_global_load_lds(
      (const __attribute__((address_space(1))) unsigned int*)g,
      (__attribute__((address_space(3))) unsigned int*)lds, 16, 0, 0);
}

// r17: B direct-from-L2 (r12 repaired via frag-major pre-pack). LDS holds
// ONLY the A double-buffer (2x32KB); B frags load as 1KB-contiguous
// wave-segments from the packed panel (L2-hot per XCD). 2 barriers/tile:
//   - P2-end: seals all waves' A(T) LDS reads (a1 waited before P2 MFMA,
//     a0 waited before P1 MFMA) -> STAGE A(T+2) into cur at P3 is safe.
//   - P4-mid (post-vmcnt(12)): A(T+1) landed (12 = B'(T+1)x8 + A(T+2)x4
//     newer ops) and visible to all -> rdA(nxt) safe. Never vmcnt 0.
// B regs double-buffered by tile parity (named sets, static indexing).
// Keeps: T1 XCD swizzle, T2 LDS swizzle on A, setprio, 16x16x32 MFMA,
// r15 epilogues (fused softmax / LDS-bounce vectorized C-write).
template <int SOFTMAX>
__global__ __launch_bounds__(512, 2)
void gemm8(const unsigned short* __restrict__ A,
           const unsigned short* __restrict__ Bp,
           void* __restrict__ Cout) {
  extern __shared__ __align__(16) char ldsc[];

  const int tid  = threadIdx.x;
  const int lane = tid & 63;
  const int wid  = tid >> 6;
  const int wm = wid >> 2, wn = wid & 3;       // wave tile: 128 rows x 64 cols
  const int fr = lane & 15, fq = lane >> 4;

  // T1: bijective XCD swizzle (512 blocks, 8 XCDs, 64 blocks/chunk).
  const int bid0 = blockIdx.x;
  const int bid  = ((bid0 & 7) << 6) | (bid0 >> 3);
  const int brow = (bid >> 2) * BM;
  const int bcol = (bid & 3) * BN;

  // A staging: linear LDS dest + inverse-swizzled global src (rule #21).
  const int srow  = tid >> 3;                              // 0..63
  const int sslot = (tid & 7) ^ (srow & 7);
  const unsigned short* gA = A + (size_t)(brow + srow) * KD + sslot * 8;

  f32x4  acc[8][4] = {};
  bf16x8 a0[4][2], a1[4][2];
  bf16x8 b01A[2][2], b23A[2][2], b01B[2][2], b23B[2][2];

  auto STAGE = [&](int h, int kt, int b) {
    const unsigned short* gu = gA + (size_t)(h * 128) * KD + kt * BK;
    char* du = ldsc + b * ABUF + h * HALF + (wid << 10);
    gload_lds16(gu, du);
    gload_lds16(gu + (size_t)64 * KD, du + 8192);
  };

  auto rdA = [&](int b, bf16x8 (*dst)[2], int mBase) {
    const char* base = ldsc + b * ABUF + wm * HALF;
    #pragma unroll
    for (int mm = 0; mm < 4; ++mm) {
      const int r = (mBase + mm) * 16 + fr;
      #pragma unroll
      for (int ks = 0; ks < 2; ++ks)
        dst[mm][ks] = *(const bf16x8*)(base + (r << 7) +
                        ((ks * 64 + fq * 16) ^ ((r & 7) << 4)));
    }
  };
  // B frag: 64 lanes read 64 consecutive 16B chunks (1KB segment, L2-hot).
  auto gldB = [&](int kt, int nBase, bf16x8 (*dst)[2]) {
    #pragma unroll
    for (int nn = 0; nn < 2; ++nn) {
      const int n16 = (bcol >> 4) + (wn << 2) + nBase + nn;
      #pragma unroll
      for (int ks = 0; ks < 2; ++ks) {
        const size_t c = (((size_t)(n16 * 16 + kt) << 1) + ks) * 64 + lane;
        dst[nn][ks] = *(const bf16x8*)(Bp + c * 8);
      }
    }
  };
  auto MFMA16 = [&](int mBase, int nBase, bf16x8 (*af)[2], bf16x8 (*bf)[2]) {
    __builtin_amdgcn_s_setprio(1);
    #pragma unroll
    for (int ks = 0; ks < 2; ++ks)
      #pragma unroll
      for (int mm = 0; mm < 4; ++mm)
        #pragma unroll
        for (int nn = 0; nn < 2; ++nn)
          acc[mBase + mm][nBase + nn] = __builtin_amdgcn_mfma_f32_16x16x32_bf16(
              af[mm][ks], bf[nn][ks], acc[mBase + mm][nBase + nn], 0, 0, 0);
    __builtin_amdgcn_s_setprio(0);
  };

  // On entry: a0 = A(T) m0-3 (read prev P4); bC01/bC23 = B'(T) (loaded prev
  // tile); A(T) in cur, A(T+1) in nxt (landed, visible).
  auto tileStep = [&](int T, int cur, int nxt,
                      bf16x8 (*bC01)[2], bf16x8 (*bC23)[2],
                      bf16x8 (*bN01)[2], bf16x8 (*bN23)[2]) {
    const int tp1 = (T + 1 < NT) ? T + 1 : NT - 1;
    const int tp2 = (T + 2 < NT) ? T + 2 : NT - 1;

    // P1: read a1(T) | B'(T+1) n01 | MFMA (a0, b01)
    rdA(cur, a1, 4);
    gldB(tp1, 0, bN01);
    MFMA16(0, 0, a0, bC01);

    // P2: B'(T+1) n23 | MFMA (a1, b01)
    gldB(tp1, 2, bN23);
    MFMA16(4, 0, a1, bC01);
    __builtin_amdgcn_s_barrier();            // P2-end: all A(T) reads sealed

    // P3: stage A(T+2) -> cur (safe: sealed above) | MFMA (a1, b23)
    STAGE(0, tp2, cur);
    STAGE(1, tp2, cur);
    MFMA16(4, 2, a1, bC23);

    // P4: A(T+1) visibility | MFMA (a0, b23) | pre-read a0(T+1)
    // queue: [A(T+1)x4, B'(T+1)x8, A(T+2)x4] -> vmcnt(12) retires A(T+1).
    asm volatile("s_waitcnt vmcnt(12)" ::: "memory");
    __builtin_amdgcn_s_barrier();            // P4-mid: A(T+1) visible to all
    MFMA16(0, 2, a0, bC23);
    rdA(nxt, a0, 0);                         // a0(T+1) for next tile's P1
  };

  // --- prologue: A(0)->buf0, A(1)->buf1, B'(0) -> regs ---
  STAGE(0, 0, 0); STAGE(1, 0, 0);                    // A(0): 4 loads
  STAGE(0, 1, 1); STAGE(1, 1, 1);                    // A(1): 4 loads
  gldB(0, 0, b01A); gldB(0, 2, b23A);                // B'(0): 8 loads
  asm volatile("s_waitcnt vmcnt(12)" ::: "memory");  // A(0) landed
  __builtin_amdgcn_s_barrier();
  rdA(0, a0, 0);

  for (int T = 0; T < NT; T += 2) {
    tileStep(T,     0, 1, b01A, b23A, b01B, b23B);
    tileStep(T + 1, 1, 0, b01B, b23B, b01A, b23A);
  }

  if constexpr (SOFTMAX) {
    // logits = acc/4; softmax over the wave's 64-col block (= one head block)
    unsigned short* attn = reinterpret_cast<unsigned short*>(Cout);
    constexpr float CEXP = 0.25f * 1.44269504088896340736f; // log2(e)/4
    #pragma unroll
    for (int m = 0; m < 8; ++m) {
      const int row = brow + wm * 128 + m * 16 + fq * 4;
      #pragma unroll
      for (int j = 0; j < 4; ++j) {
        float v0 = acc[m][0][j], v1 = acc[m][1][j];
        float v2 = acc[m][2][j], v3 = acc[m][3][j];
        float mx = fmaxf(fmaxf(v0, v1), fmaxf(v2, v3));
        #pragma unroll
        for (int s = 1; s < 16; s <<= 1) mx = fmaxf(mx, __shfl_xor(mx, s, 64));
        float p0 = exp2f((v0 - mx) * CEXP);
        float p1 = exp2f((v1 - mx) * CEXP);
        float p2 = exp2f((v2 - mx) * CEXP);
        float p3 = exp2f((v3 - mx) * CEXP);
        float sm = p0 + p1 + p2 + p3;
        #pragma unroll
        for (int s = 1; s < 16; s <<= 1) sm += __shfl_xor(sm, s, 64);
        const float inv = 1.0f / sm;
        unsigned short* dst =
            attn + (size_t)(row + j) * ND + (bcol + wn * 64 + fr);
        dst[0]  = f2bf_rne(p0 * inv);
        dst[16] = f2bf_rne(p1 * inv);
        dst[32] = f2bf_rne(p2 * inv);
        dst[48] = f2bf_rne(p3 * inv);
      }
    }
  } else {
    // Vectorized f32 C-write via wave-private 16KB LDS bounce (r15).
    float* Cf = reinterpret_cast<float*>(Cout);
    char* wlds = ldsc + wid * 16384;
    #pragma unroll
    for (int h = 0; h < 2; ++h) {
      asm volatile("" ::: "memory");
      #pragma unroll
      for (int mm = 0; mm < 4; ++mm)
        #pragma unroll
        for (int n = 0; n < 4; ++n)
          #pragma unroll
          for (int j = 0; j < 4; ++j)
            *(float*)(wlds + (((mm * 16 + fq * 4 + j) << 6) + n * 16 + fr) * 4)
                = acc[4 * h + mm][n][j];
      asm volatile("s_waitcnt lgkmcnt(0)" ::: "memory"); // scatter visible
      const int rbase = brow + wm * 128 + h * 64;
      #pragma unroll
      for (int i = 0; i < 16; ++i) {
        const int idx16 = i * 64 + lane;     // 16B chunk id within 64x64 tile
        const int rl = idx16 >> 4;
        const int c4 = (idx16 & 15) << 2;
        f32x4 v = *(const f32x4*)(wlds + (size_t)idx16 * 16);
        *(f32x4*)(&Cf[(size_t)(rbase + rl) * ND + (bcol + wn * 64 + c4)]) = v;
      }
      asm volatile("s_waitcnt lgkmcnt(0)" ::: "memory"); // gather done pre-overwrite
    }
  }
}

extern "C" void kernel_launch(void* const* d_in, const int* in_sizes, int n_in,
                              void* d_out, int out_size, void* d_ws, size_t ws_size,
                              hipStream_t stream) {
  const float* x  = (const float*)d_in[0];   // [4,8192,1024] f32
  const float* W1 = (const float*)d_in[1];   // [3072,1024]  f32 (rows 0..1023 = Wq)
  const float* W2 = (const float*)d_in[2];   // [1024,1024]  f32
  float* out = (float*)d_out;

  char* ws = (char*)d_ws;
  unsigned short* xb   = (unsigned short*)(ws);
  unsigned short* w1p  = (unsigned short*)(ws + (size_t)67108864);
  unsigned short* w2p  = (unsigned short*)(ws + (size_t)69206016);
  unsigned short* attn = (unsigned short*)(ws + (size_t)71303168);

  hipFuncSetAttribute(reinterpret_cast<const void*>(gemm8<1>),
                      hipFuncAttributeMaxDynamicSharedMemorySize, 131072);
  hipFuncSetAttribute(reinterpret_cast<const void*>(gemm8<0>),
                      hipFuncAttributeMaxDynamicSharedMemorySize, 131072);

  prep<<<2048, 256, 0, stream>>>(x, W1, W2, xb, w1p, w2p);

  const int nblk = (MTOT / BM) * (ND / BN);   // 128 * 4 = 512
  gemm8<1><<<nblk, 512, 131072, stream>>>(xb, w1p, (void*)attn);
  gemm8<0><<<nblk, 512, 131072, stream>>>(attn, w2p, (void*)out);
}

// Round 18
// 195.267 us; speedup vs baseline: 1.7073x; 1.7073x over previous
//
#include <hip/hip_runtime.h>
#include <hip/hip_bf16.h>
#include <stdint.h>

// B=4, S=8192, E=1024, heads=16 -> math collapses to:
//   Q = x @ W1[0:1024].T ; A = per-64-col-block softmax(Q/4) ; out = A @ W2.T
static constexpr int MTOT = 32768;
static constexpr int KD   = 1024;
static constexpr int ND   = 1024;

static constexpr int BM = 256, BN = 256, BK = 64;
static constexpr int NT = KD / BK;              // 16 K-tiles (even)
static constexpr int ABUF = 32768;              // one A buffer (256x64 bf16)
static constexpr int HALF = 16384;              // one A unit (128 rows x 64 cols)

typedef __bf16 bf16x8 __attribute__((ext_vector_type(8)));
typedef float  f32x4  __attribute__((ext_vector_type(4)));

__device__ __forceinline__ unsigned short f2bf_rne(float f) {
  union { float f; uint32_t u; } c; c.f = f;
  uint32_t u = c.u;
  return (unsigned short)((u + 0x7fffu + ((u >> 16) & 1u)) >> 16);
}

// Cast x -> bf16 row-major; pack W1q/W2 -> frag-major bf16:
//   chunk c = ((n16*16 + kt)*2 + ks)*64 + lane  holds
//   W[n16*16 + (lane&15)][kt*64 + ks*32 + (lane>>4)*8 .. +8]
// so a wave's MFMA B-frag load is 64 consecutive 16B = 1KB contiguous.
__global__ void prep(const float* __restrict__ x,
                     const float* __restrict__ W1,
                     const float* __restrict__ W2,
                     unsigned short* __restrict__ xb,
                     unsigned short* __restrict__ w1p,
                     unsigned short* __restrict__ w2p) {
  constexpr int n4x = MTOT * KD / 4;
  constexpr int nChunk = (KD >> 4) * NT * 2 * 64;   // 131072 per matrix
  const int idx = blockIdx.x * blockDim.x + threadIdx.x;
  const int stride = gridDim.x * blockDim.x;
  for (int i = idx; i < n4x; i += stride) {
    float4 v = reinterpret_cast<const float4*>(x)[i];
    ushort4 o;
    o.x = f2bf_rne(v.x); o.y = f2bf_rne(v.y);
    o.z = f2bf_rne(v.z); o.w = f2bf_rne(v.w);
    reinterpret_cast<ushort4*>(xb)[i] = o;
  }
  for (int i = idx; i < 2 * nChunk; i += stride) {
    const int m = (i >= nChunk) ? 1 : 0;
    const int c = i - m * nChunk;
    const float* W = m ? W2 : W1;            // W1 rows 0..1023 = Wq
    unsigned short* P = m ? w2p : w1p;
    const int lane = c & 63;
    const int ks   = (c >> 6) & 1;
    const int kt   = (c >> 7) & 15;
    const int n16  = c >> 11;
    const int row  = n16 * 16 + (lane & 15);
    const int k    = kt * 64 + ks * 32 + (lane >> 4) * 8;
    const float* s = W + (size_t)row * KD + k;
    float4 v0 = reinterpret_cast<const float4*>(s)[0];
    float4 v1 = reinterpret_cast<const float4*>(s)[1];
    ushort4 o0, o1;
    o0.x = f2bf_rne(v0.x); o0.y = f2bf_rne(v0.y);
    o0.z = f2bf_rne(v0.z); o0.w = f2bf_rne(v0.w);
    o1.x = f2bf_rne(v1.x); o1.y = f2bf_rne(v1.y);
    o1.z = f2bf_rne(v1.z); o1.w = f2bf_rne(v1.w);
    reinterpret_cast<ushort4*>(P + (size_t)c * 8)[0] = o0;
    reinterpret_cast<ushort4*>(P + (size_t)c * 8)[1] = o1;
  }
}

__device__ __forceinline__ void gload_lds16(const void* g, void* lds) {
  __builtin_amdgcn_global_load_lds(
      (const __attribute__((address_space(1))) unsigned int*)g,
      (__attribute__((address_space(3))) unsigned int*)lds, 16, 0, 0);
}

// r18: B direct-from-L2 (frag-major pack), SINGLE-buffered B regs (plain
// captured locals, static indices -- no rule-#20 pointer passing). B reloads
// just-in-time with >=1-cluster lead: b01(T+1)@P3 (dead after P2),
// b23(T+1)@P4 after its last MFMA (register WAR orders the load).
// LDS holds only the A double-buffer. 2 barriers/tile:
//  - P2-end: seals all waves' A(T) reads -> STAGE A(T+2)->cur at P3 safe.
//  - P4-mid post-vmcnt(8): in-order queue [.., A(T+1)x4, b23(T)x4 |
//    A(T+2)x4, b01(T+1)x4] -> allowing newest 8 retires A(T+1). Never 0.
// Keeps: T1 XCD swizzle, T2 LDS swizzle on A, setprio, r15 epilogues.
template <int SOFTMAX>
__global__ __launch_bounds__(512, 2)
void gemm8(const unsigned short* __restrict__ A,
           const unsigned short* __restrict__ Bp,
           void* __restrict__ Cout) {
  extern __shared__ __align__(16) char ldsc[];

  const int tid  = threadIdx.x;
  const int lane = tid & 63;
  const int wid  = tid >> 6;
  const int wm = wid >> 2, wn = wid & 3;       // wave tile: 128 rows x 64 cols
  const int fr = lane & 15, fq = lane >> 4;

  // T1: bijective XCD swizzle (512 blocks, 8 XCDs, 64 blocks/chunk).
  const int bid0 = blockIdx.x;
  const int bid  = ((bid0 & 7) << 6) | (bid0 >> 3);
  const int brow = (bid >> 2) * BM;
  const int bcol = (bid & 3) * BN;

  // A staging: linear LDS dest + inverse-swizzled global src (rule #21).
  const int srow  = tid >> 3;                              // 0..63
  const int sslot = (tid & 7) ^ (srow & 7);
  const unsigned short* gA = A + (size_t)(brow + srow) * KD + sslot * 8;

  f32x4  acc[8][4] = {};
  bf16x8 a0[4][2], a1[4][2], b01[2][2], b23[2][2];

  auto STAGE = [&](int h, int kt, int b) {
    const unsigned short* gu = gA + (size_t)(h * 128) * KD + kt * BK;
    char* du = ldsc + b * ABUF + h * HALF + (wid << 10);
    gload_lds16(gu, du);
    gload_lds16(gu + (size_t)64 * KD, du + 8192);
  };

  auto rdA = [&](int b, bf16x8 (*dst)[2], int mBase) {
    const char* base = ldsc + b * ABUF + wm * HALF;
    #pragma unroll
    for (int mm = 0; mm < 4; ++mm) {
      const int r = (mBase + mm) * 16 + fr;
      #pragma unroll
      for (int ks = 0; ks < 2; ++ks)
        dst[mm][ks] = *(const bf16x8*)(base + (r << 7) +
                        ((ks * 64 + fq * 16) ^ ((r & 7) << 4)));
    }
  };
  // B frag: 64 lanes read 64 consecutive 16B chunks (1KB segment, L2-hot).
  auto gldB = [&](int kt, int nBase, bf16x8 (*dst)[2]) {
    #pragma unroll
    for (int nn = 0; nn < 2; ++nn) {
      const int n16 = (bcol >> 4) + (wn << 2) + nBase + nn;
      #pragma unroll
      for (int ks = 0; ks < 2; ++ks) {
        const size_t c = (((size_t)(n16 * 16 + kt) << 1) + ks) * 64 + lane;
        dst[nn][ks] = *(const bf16x8*)(Bp + c * 8);
      }
    }
  };
  auto MFMA16 = [&](int mBase, int nBase, bf16x8 (*af)[2], bf16x8 (*bf)[2]) {
    __builtin_amdgcn_s_setprio(1);
    #pragma unroll
    for (int ks = 0; ks < 2; ++ks)
      #pragma unroll
      for (int mm = 0; mm < 4; ++mm)
        #pragma unroll
        for (int nn = 0; nn < 2; ++nn)
          acc[mBase + mm][nBase + nn] = __builtin_amdgcn_mfma_f32_16x16x32_bf16(
              af[mm][ks], bf[nn][ks], acc[mBase + mm][nBase + nn], 0, 0, 0);
    __builtin_amdgcn_s_setprio(0);
  };

  // On entry: a0 = A(T) m0-3; b01/b23 = B'(T); A(T) in cur, A(T+1) in nxt.
  auto tileStep = [&](int T, int cur, int nxt) {
    const int tp1 = (T + 1 < NT) ? T + 1 : NT - 1;
    const int tp2 = (T + 2 < NT) ? T + 2 : NT - 1;

    // P1: read a1(T) | MFMA (a0, b01)
    rdA(cur, a1, 4);
    MFMA16(0, 0, a0, b01);

    // P2: MFMA (a1, b01); b01 dead after
    MFMA16(4, 0, a1, b01);
    __builtin_amdgcn_s_barrier();            // P2-end: all A(T) reads sealed

    // P3: stage A(T+2)->cur | reload b01 <- B'(T+1) | MFMA (a1, b23)
    STAGE(0, tp2, cur);
    STAGE(1, tp2, cur);
    gldB(tp1, 0, b01);                       // lead ~1.5 clusters to next P1
    MFMA16(4, 2, a1, b23);

    // P4: A(T+1) visibility | MFMA (a0, b23) | refills
    asm volatile("s_waitcnt vmcnt(8)" ::: "memory"); // retires A(T+1) (see audit)
    __builtin_amdgcn_s_barrier();            // P4-mid: A(T+1) visible to all
    MFMA16(0, 2, a0, b23);
    rdA(nxt, a0, 0);                         // a0(T+1); WAR after MFMA above
    gldB(tp1, 2, b23);                       // b23(T+1); WAR after MFMA above
  };

  // --- prologue: A(0)->buf0, B'(0), A(1)->buf1 ---
  STAGE(0, 0, 0); STAGE(1, 0, 0);                    // A(0): 4 loads
  gldB(0, 0, b01); gldB(0, 2, b23);                  // B'(0): 8 loads
  STAGE(0, 1, 1); STAGE(1, 1, 1);                    // A(1): 4 loads
  asm volatile("s_waitcnt vmcnt(12)" ::: "memory");  // A(0) landed
  __builtin_amdgcn_s_barrier();
  rdA(0, a0, 0);

  for (int T = 0; T < NT; T += 2) {
    tileStep(T,     0, 1);
    tileStep(T + 1, 1, 0);
  }

  if constexpr (SOFTMAX) {
    // logits = acc/4; softmax over the wave's 64-col block (= one head block)
    unsigned short* attn = reinterpret_cast<unsigned short*>(Cout);
    constexpr float CEXP = 0.25f * 1.44269504088896340736f; // log2(e)/4
    #pragma unroll
    for (int m = 0; m < 8; ++m) {
      const int row = brow + wm * 128 + m * 16 + fq * 4;
      #pragma unroll
      for (int j = 0; j < 4; ++j) {
        float v0 = acc[m][0][j], v1 = acc[m][1][j];
        float v2 = acc[m][2][j], v3 = acc[m][3][j];
        float mx = fmaxf(fmaxf(v0, v1), fmaxf(v2, v3));
        #pragma unroll
        for (int s = 1; s < 16; s <<= 1) mx = fmaxf(mx, __shfl_xor(mx, s, 64));
        float p0 = exp2f((v0 - mx) * CEXP);
        float p1 = exp2f((v1 - mx) * CEXP);
        float p2 = exp2f((v2 - mx) * CEXP);
        float p3 = exp2f((v3 - mx) * CEXP);
        float sm = p0 + p1 + p2 + p3;
        #pragma unroll
        for (int s = 1; s < 16; s <<= 1) sm += __shfl_xor(sm, s, 64);
        const float inv = 1.0f / sm;
        unsigned short* dst =
            attn + (size_t)(row + j) * ND + (bcol + wn * 64 + fr);
        dst[0]  = f2bf_rne(p0 * inv);
        dst[16] = f2bf_rne(p1 * inv);
        dst[32] = f2bf_rne(p2 * inv);
        dst[48] = f2bf_rne(p3 * inv);
      }
    }
  } else {
    // Vectorized f32 C-write via wave-private 16KB LDS bounce (r15).
    float* Cf = reinterpret_cast<float*>(Cout);
    char* wlds = ldsc + wid * 16384;
    #pragma unroll
    for (int h = 0; h < 2; ++h) {
      asm volatile("" ::: "memory");
      #pragma unroll
      for (int mm = 0; mm < 4; ++mm)
        #pragma unroll
        for (int n = 0; n < 4; ++n)
          #pragma unroll
          for (int j = 0; j < 4; ++j)
            *(float*)(wlds + (((mm * 16 + fq * 4 + j) << 6) + n * 16 + fr) * 4)
                = acc[4 * h + mm][n][j];
      asm volatile("s_waitcnt lgkmcnt(0)" ::: "memory"); // scatter visible
      const int rbase = brow + wm * 128 + h * 64;
      #pragma unroll
      for (int i = 0; i < 16; ++i) {
        const int idx16 = i * 64 + lane;     // 16B chunk id within 64x64 tile
        const int rl = idx16 >> 4;
        const int c4 = (idx16 & 15) << 2;
        f32x4 v = *(const f32x4*)(wlds + (size_t)idx16 * 16);
        *(f32x4*)(&Cf[(size_t)(rbase + rl) * ND + (bcol + wn * 64 + c4)]) = v;
      }
      asm volatile("s_waitcnt lgkmcnt(0)" ::: "memory"); // gather done pre-overwrite
    }
  }
}

extern "C" void kernel_launch(void* const* d_in, const int* in_sizes, int n_in,
                              void* d_out, int out_size, void* d_ws, size_t ws_size,
                              hipStream_t stream) {
  const float* x  = (const float*)d_in[0];   // [4,8192,1024] f32
  const float* W1 = (const float*)d_in[1];   // [3072,1024]  f32 (rows 0..1023 = Wq)
  const float* W2 = (const float*)d_in[2];   // [1024,1024]  f32
  float* out = (float*)d_out;

  char* ws = (char*)d_ws;
  unsigned short* xb   = (unsigned short*)(ws);
  unsigned short* w1p  = (unsigned short*)(ws + (size_t)67108864);
  unsigned short* w2p  = (unsigned short*)(ws + (size_t)69206016);
  unsigned short* attn = (unsigned short*)(ws + (size_t)71303168);

  hipFuncSetAttribute(reinterpret_cast<const void*>(gemm8<1>),
                      hipFuncAttributeMaxDynamicSharedMemorySize, 131072);
  hipFuncSetAttribute(reinterpret_cast<const void*>(gemm8<0>),
                      hipFuncAttributeMaxDynamicSharedMemorySize, 131072);

  prep<<<2048, 256, 0, stream>>>(x, W1, W2, xb, w1p, w2p);

  const int nblk = (MTOT / BM) * (ND / BN);   // 128 * 4 = 512
  gemm8<1><<<nblk, 512, 131072, stream>>>(xb, w1p, (void*)attn);
  gemm8<0><<<nblk, 512, 131072, stream>>>(attn, w2p, (void*)out);
}